// Round 7
// baseline (233.823 us; speedup 1.0000x reference)
//
#include <hip/hip_runtime.h>
#include <math.h>

#define N_ROWS 400      // bs*Q
#define M_ROWS 80       // = 5*16
#define K_CLS  134
#define PN     12544
#define PFULL  65536    // 256*256
#define WORDS  (PFULL / 32)   // 2048 bitmap words == full-grid t-steps
#define NSUB   25       // 400/16 n-subtiles
#define KS     64       // k-chunks (full-grid split)
#define TCH    (WORDS / KS)   // 32 t-steps per chunk
#define ITERS  (TCH / 4)      // 8 t-steps per wave
#define NM     (N_ROWS * M_ROWS)
#define NBLK   (NSUB * KS)    // 1600 gemm blocks

typedef __attribute__((ext_vector_type(4))) float  f32x4;
typedef __attribute__((ext_vector_type(8))) __bf16 bf16x8;

__device__ __forceinline__ float wave_reduce_sum(float v) {
#pragma unroll
    for (int off = 32; off > 0; off >>= 1) v += __shfl_down(v, off, 64);
    return v;
}

// --- block 0: build selection bitmap + zero ysum accumulator.
//     blocks 1..25: softmax stats. ---
__global__ __launch_bounds__(1024) void sort_softmax_kernel(
        const int* __restrict__ point_idx,
        unsigned int* __restrict__ bitmap_g,
        float* __restrict__ ysum_acc,
        const float* __restrict__ pred_logits,
        float* __restrict__ rowmax, float* __restrict__ rowsum) {
    int tid = threadIdx.x;
    if (blockIdx.x == 0) {
        __shared__ unsigned int bits[WORDS];   // 8 KB
        bits[tid] = 0u; bits[tid + 1024] = 0u;
        if (tid < M_ROWS) ysum_acc[tid] = 0.f;
        __syncthreads();
        for (int i = tid; i < PN; i += 1024) {
            int p = point_idx[i];
            atomicOr(&bits[p >> 5], 1u << (p & 31));
        }
        __syncthreads();
        bitmap_g[tid]        = bits[tid];
        bitmap_g[tid + 1024] = bits[tid + 1024];
    } else {
        int wave = tid >> 6, lane = tid & 63;
        int n = (blockIdx.x - 1) * 16 + wave;       // < 400
        const float* row = pred_logits + n * K_CLS;
        float mx = -1e30f;
        for (int k = lane; k < K_CLS; k += 64) mx = fmaxf(mx, row[k]);
#pragma unroll
        for (int off = 32; off > 0; off >>= 1) mx = fmaxf(mx, __shfl_down(mx, off, 64));
        mx = __shfl(mx, 0, 64);
        float se = 0.f;
        for (int k = lane; k < K_CLS; k += 64) se += expf(row[k] - mx);
        se = wave_reduce_sum(se);
        if (lane == 0) { rowmax[n] = mx; rowsum[n] = se; }
    }
}

// --- build Y' directly as bf16 MFMA B-fragments, plus sel-fragment (slot 5)
//     and ysum via atomicAdd (zeroed by sort kernel, stream-ordered). ---
__global__ __launch_bounds__(512) void buildY_kernel(
        const float* __restrict__ tgt_masks,
        const unsigned int* __restrict__ bitmap_g,
        bf16x8* __restrict__ Yb, float* __restrict__ ysum_acc) {
    __shared__ float smem[128];
    int b = blockIdx.x;
    int j = b >> 8, tch = b & 255;
    int wave = threadIdx.x >> 6, lane = threadIdx.x & 63;
    int colL = lane & 15, quad = lane >> 4;
    int t = tch * 8 + wave;
    unsigned int w = bitmap_g[t];
    bf16x8 v;
    if (j < 5) {
        int m = 16 * j + colL;
        const float* yrow = tgt_masks + (size_t)m * PFULL + t * 32 + quad * 8;
        f32x4 ya = *(const f32x4*)(yrow);
        f32x4 yc = *(const f32x4*)(yrow + 4);
        float acc = 0.f;
#pragma unroll
        for (int jj = 0; jj < 4; ++jj) {
            float va = ((w >> (quad * 8 + jj)) & 1u)     ? (ya[jj] > 0.5f ? 1.f : 0.f) : 0.f;
            float vc = ((w >> (quad * 8 + jj + 4)) & 1u) ? (yc[jj] > 0.5f ? 1.f : 0.f) : 0.f;
            v[jj] = (__bf16)va; v[jj + 4] = (__bf16)vc;
            acc += va + vc;
        }
        Yb[((size_t)t * 6 + j) * 64 + lane] = v;
        acc += __shfl_down(acc, 32, 64);
        acc += __shfl_down(acc, 16, 64);
        if (quad == 0) smem[wave * 16 + colL] = acc;
        __syncthreads();
        if (threadIdx.x < 16) {
            float s = 0.f;
#pragma unroll
            for (int wv = 0; wv < 8; ++wv) s += smem[wv * 16 + threadIdx.x];
            atomicAdd(&ysum_acc[16 * j + threadIdx.x], s);
        }
    } else {
        // sel fragment: column 0 only
#pragma unroll
        for (int jj = 0; jj < 8; ++jj) {
            float sv = (colL == 0 && ((w >> (quad * 8 + jj)) & 1u)) ? 1.f : 0.f;
            v[jj] = (__bf16)sv;
        }
        Yb[((size_t)t * 6 + 5) * 64 + lane] = v;
    }
}

// --- full-grid fused GEMM. launch_bounds(256,2): 256 unified VGPR+AGPR
//     per wave so the software pipeline (A depth-4 + B 2-slot) survives
//     register allocation (at (256,4) the compiler de-pipelined: VGPR=56).
//     A (HBM) prefetched 4 iters ahead; B (L2/L3) refilled 2 ahead. ---
__global__ __launch_bounds__(256, 2) void gemm_full_kernel(
        const float* __restrict__ pred_masks,
        const bf16x8* __restrict__ Yb,
        float* __restrict__ xypart, float* __restrict__ sypart,
        float* __restrict__ rowS, float* __restrict__ rowSP) {
    __shared__ float red[4][20][64];       // 20 KB
    __shared__ float rS[4][16], rSP[4][16];
    int tid = threadIdx.x;
    int wave = tid >> 6, lane = tid & 63;
    int colL = lane & 15, quad = lane >> 4;
    int nsub = blockIdx.x % NSUB, ch = blockIdx.x / NSUB;  // nsub fastest
    int n0 = nsub * 16;
    int t0 = ch * TCH + wave * ITERS;
    const float* rowp = pred_masks + (size_t)(n0 + colL) * PFULL;
    int kbase = t0 * 32 + quad * 8;

    f32x4 accX[5], accS[5];
    f32x4 zero = {0.f, 0.f, 0.f, 0.f};
#pragma unroll
    for (int j = 0; j < 5; ++j) { accX[j] = zero; accS[j] = zero; }
    f32x4 acc5S = zero, acc5P = zero;

    // A prefetch: depth 4 (8 loads / 128B per lane in flight)
    f32x4 PA[4], PB[4];
#pragma unroll
    for (int d = 0; d < 4; ++d) {
        PA[d] = *(const f32x4*)(rowp + kbase + d * 32);
        PB[d] = *(const f32x4*)(rowp + kbase + d * 32 + 4);
    }
    // B double buffer: static 2-slot, fully unrolled indexing
    bf16x8 Bbuf[2][6];
#pragma unroll
    for (int s = 0; s < 2; ++s) {
        const bf16x8* q = Yb + ((size_t)(t0 + s) * 6) * 64 + lane;
#pragma unroll
        for (int j = 0; j < 6; ++j) Bbuf[s][j] = q[j * 64];
    }

#pragma unroll
    for (int i = 0; i < ITERS; ++i) {
        const int s = i & 1;
        f32x4 xa = PA[0], xb = PB[0];
        PA[0] = PA[1]; PB[0] = PB[1];
        PA[1] = PA[2]; PB[1] = PB[2];
        PA[2] = PA[3]; PB[2] = PB[3];
        if (i + 4 < ITERS) {
            PA[3] = *(const f32x4*)(rowp + kbase + (i + 4) * 32);
            PB[3] = *(const f32x4*)(rowp + kbase + (i + 4) * 32 + 4);
        }
        float xsv[8];
        *(f32x4*)(xsv) = xa; *(f32x4*)(xsv + 4) = xb;
        bf16x8 aX, aS, aSP;
#pragma unroll
        for (int jj = 0; jj < 8; ++jj) {
            float x  = xsv[jj];
            float ax = fabsf(x);
            float e  = __expf(-ax);
            float den = 1.f + e;
            float inv = __builtin_amdgcn_rcpf(den);
            float sig = (x >= 0.f) ? inv : e * inv;
            float sp  = fmaxf(x, 0.f) + __logf(den);
            aX[jj] = (__bf16)x; aS[jj] = (__bf16)sig; aSP[jj] = (__bf16)sp;
        }
        accX[0] = __builtin_amdgcn_mfma_f32_16x16x32_bf16(aX, Bbuf[s][0], accX[0], 0, 0, 0);
        accS[0] = __builtin_amdgcn_mfma_f32_16x16x32_bf16(aS, Bbuf[s][0], accS[0], 0, 0, 0);
        accX[1] = __builtin_amdgcn_mfma_f32_16x16x32_bf16(aX, Bbuf[s][1], accX[1], 0, 0, 0);
        accS[1] = __builtin_amdgcn_mfma_f32_16x16x32_bf16(aS, Bbuf[s][1], accS[1], 0, 0, 0);
        accX[2] = __builtin_amdgcn_mfma_f32_16x16x32_bf16(aX, Bbuf[s][2], accX[2], 0, 0, 0);
        accS[2] = __builtin_amdgcn_mfma_f32_16x16x32_bf16(aS, Bbuf[s][2], accS[2], 0, 0, 0);
        accX[3] = __builtin_amdgcn_mfma_f32_16x16x32_bf16(aX, Bbuf[s][3], accX[3], 0, 0, 0);
        accS[3] = __builtin_amdgcn_mfma_f32_16x16x32_bf16(aS, Bbuf[s][3], accS[3], 0, 0, 0);
        accX[4] = __builtin_amdgcn_mfma_f32_16x16x32_bf16(aX, Bbuf[s][4], accX[4], 0, 0, 0);
        accS[4] = __builtin_amdgcn_mfma_f32_16x16x32_bf16(aS, Bbuf[s][4], accS[4], 0, 0, 0);
        acc5S   = __builtin_amdgcn_mfma_f32_16x16x32_bf16(aS,  Bbuf[s][5], acc5S, 0, 0, 0);
        acc5P   = __builtin_amdgcn_mfma_f32_16x16x32_bf16(aSP, Bbuf[s][5], acc5P, 0, 0, 0);
        // refill slot s for iteration i+2
        if (i + 2 < ITERS) {
            const bf16x8* q = Yb + ((size_t)(t0 + i + 2) * 6) * 64 + lane;
#pragma unroll
            for (int j = 0; j < 6; ++j) Bbuf[s][j] = q[j * 64];
        }
    }

    // ---- epilogue pass 1: xy partials + row sums ----
#pragma unroll
    for (int j = 0; j < 5; ++j)
#pragma unroll
        for (int r = 0; r < 4; ++r) red[wave][j * 4 + r][lane] = accX[j][r];
    if (colL == 0) {
#pragma unroll
        for (int r = 0; r < 4; ++r) {
            rS[wave][quad * 4 + r]  = acc5S[r];
            rSP[wave][quad * 4 + r] = acc5P[r];
        }
    }
    __syncthreads();
#pragma unroll
    for (int v0 = 0; v0 < 5; ++v0) {
        int v = wave * 5 + v0;
        float s = red[0][v][lane] + red[1][v][lane] + red[2][v][lane] + red[3][v][lane];
        int j = v >> 2, r = v & 3;
        int n = n0 + quad * 4 + r, m = 16 * j + colL;   // verified C/D layout
        xypart[(size_t)ch * NM + n * M_ROWS + m] = s;
    }
    if (tid < 16) {
        rowS[ch * N_ROWS + n0 + tid] = rS[0][tid] + rS[1][tid] + rS[2][tid] + rS[3][tid];
    } else if (tid < 32) {
        int l = tid - 16;
        rowSP[ch * N_ROWS + n0 + l] = rSP[0][l] + rSP[1][l] + rSP[2][l] + rSP[3][l];
    }
    __syncthreads();
    // ---- epilogue pass 2: sy partials ----
#pragma unroll
    for (int j = 0; j < 5; ++j)
#pragma unroll
        for (int r = 0; r < 4; ++r) red[wave][j * 4 + r][lane] = accS[j][r];
    __syncthreads();
#pragma unroll
    for (int v0 = 0; v0 < 5; ++v0) {
        int v = wave * 5 + v0;
        float s = red[0][v][lane] + red[1][v][lane] + red[2][v][lane] + red[3][v][lane];
        int j = v >> 2, r = v & 3;
        int n = n0 + quad * 4 + r, m = 16 * j + colL;
        sypart[(size_t)ch * NM + n * M_ROWS + m] = s;
    }
}

// --- combine: 500 blocks; each block owns 64 idx; the 64-chunk g-reduction
//     is split across 4 lane-groups (16 g each) + LDS reduce. ---
__global__ __launch_bounds__(256) void combine_kernel(
        const float* __restrict__ logits,
        const int* __restrict__ tgt_labels,
        const float* __restrict__ rowmax,
        const float* __restrict__ rowsum,
        const float* __restrict__ rowS,
        const float* __restrict__ rowSP,
        const float* __restrict__ ysum_acc,
        const float* __restrict__ xypart,
        const float* __restrict__ sypart,
        float* __restrict__ out) {
    __shared__ float sxy[4][64], ssy[4][64], sss[4][64], ssp[4][64];
    int il = threadIdx.x & 63, q = threadIdx.x >> 6;
    int idx = blockIdx.x * 64 + il;
    int n = idx / M_ROWS, m = idx % M_ROWS;
    float xy = 0.f, sy = 0.f, ss = 0.f, sp = 0.f;
#pragma unroll
    for (int gi = 0; gi < 16; ++gi) {
        int g = q * 16 + gi;
        xy += xypart[(size_t)g * NM + idx];
        sy += sypart[(size_t)g * NM + idx];
        ss += rowS[g * N_ROWS + n];
        sp += rowSP[g * N_ROWS + n];
    }
    sxy[q][il] = xy; ssy[q][il] = sy; sss[q][il] = ss; ssp[q][il] = sp;
    __syncthreads();
    if (q == 0) {
        xy = sxy[0][il] + sxy[1][il] + sxy[2][il] + sxy[3][il];
        sy = ssy[0][il] + ssy[1][il] + ssy[2][il] + ssy[3][il];
        ss = sss[0][il] + sss[1][il] + sss[2][il] + sss[3][il];
        sp = ssp[0][il] + ssp[1][il] + ssp[2][il] + ssp[3][il];
        float ysum = ysum_acc[m];
        int tc = tgt_labels[m];
        tc = min(max(tc, 0), K_CLS - 1);
        float p = expf(logits[n * K_CLS + tc] - rowmax[n]) / rowsum[n];
        float cost_class = -p;
        float cost_mask = (sp - xy) * (1.0f / PN);
        float cost_dice = 1.f - (2.f * sy + 1.f) / (ss + ysum + 1.f);
        out[idx] = 2.f * cost_class + 5.f * cost_mask + 5.f * cost_dice;
    }
}

extern "C" void kernel_launch(void* const* d_in, const int* in_sizes, int n_in,
                              void* d_out, int out_size, void* d_ws, size_t ws_size,
                              hipStream_t stream) {
    const float* pred_logits = (const float*)d_in[0];   // (4,100,134)
    const float* pred_masks  = (const float*)d_in[1];   // (4,100,256,256)
    const int*   tgt_labels  = (const int*)d_in[2];     // (80,)
    const float* tgt_masks   = (const float*)d_in[3];   // (80,256,256)
    const int*   point_idx   = (const int*)d_in[4];     // (12544,)
    float* out = (float*)d_out;                         // (4,100,80)

    char* ws = (char*)d_ws;
    size_t off = 0;
    auto carve = [&](size_t nbytes) {
        char* p = ws + off;
        off += (nbytes + 255) & ~(size_t)255;
        return p;
    };
    // all buffers fully overwritten every launch (ysum_acc zeroed in sort
    // kernel before buildY accumulates) -> no host-side zero-init
    unsigned int* bitmap = (unsigned int*)carve(WORDS * 4);            // 8 KB
    bf16x8* Yb    = (bf16x8*)carve((size_t)WORDS * 6 * 64 * 16);       // 12.6 MB
    float* rowmax = (float*)carve(N_ROWS * 4);
    float* rowsum = (float*)carve(N_ROWS * 4);
    float* ysum_acc = (float*)carve(M_ROWS * 4);
    float* rowS   = (float*)carve((size_t)KS * N_ROWS * 4);
    float* rowSP  = (float*)carve((size_t)KS * N_ROWS * 4);
    float* xypart = (float*)carve((size_t)KS * NM * 4);                // 8.2 MB
    float* sypart = (float*)carve((size_t)KS * NM * 4);                // 8.2 MB
    (void)ws_size; (void)in_sizes; (void)n_in; (void)out_size;

    sort_softmax_kernel<<<26, 1024, 0, stream>>>(point_idx, bitmap, ysum_acc,
                                                 pred_logits, rowmax, rowsum);
    buildY_kernel<<<6 * 256, 512, 0, stream>>>(tgt_masks, bitmap, Yb, ysum_acc);
    gemm_full_kernel<<<NBLK, 256, 0, stream>>>(
        pred_masks, Yb, xypart, sypart, rowS, rowSP);
    combine_kernel<<<NM / 64, 256, 0, stream>>>(
        pred_logits, tgt_labels, rowmax, rowsum, rowS, rowSP, ysum_acc,
        xypart, sypart, out);
}

// Round 8
// 215.326 us; speedup vs baseline: 1.0859x; 1.0859x over previous
//
#include <hip/hip_runtime.h>
#include <math.h>

#define N_ROWS 400      // bs*Q
#define M_ROWS 80       // = 5*16
#define K_CLS  134
#define PN     12544    // = 392*32 selected points
#define PFULL  65536    // 256*256
#define WORDS  (PFULL / 32)   // 2048 bitmap words
#define TSTEPS 392      // PN/32 MFMA k-steps
#define NSUB   25       // 400/16 n-subtiles
#define KCG    49       // k-groups in gemm (8 t-steps per block)
#define TPB    2        // t-steps per wave
#define NM     (N_ROWS * M_ROWS)
#define CHUNK  16384    // elements per compact block
#define CPB    (PFULL / CHUNK)   // 4 chunks per row

typedef __attribute__((ext_vector_type(4))) float  f32x4;
typedef __attribute__((ext_vector_type(8))) __bf16 bf16x8;

__device__ __forceinline__ float wave_reduce_sum(float v) {
#pragma unroll
    for (int off = 32; off > 0; off >>= 1) v += __shfl_down(v, off, 64);
    return v;
}

// --- block 0: selection bitmap + per-word exclusive rank prefix + zero accs.
//     blocks 1..25: softmax stats (16 rows each, one per wave). ---
__global__ __launch_bounds__(1024) void sort_softmax_kernel(
        const int* __restrict__ point_idx,
        unsigned int* __restrict__ bitmap_g, int* __restrict__ rank_g,
        float* __restrict__ rowS_acc, float* __restrict__ rowSP_acc,
        float* __restrict__ ysum_acc,
        const float* __restrict__ pred_logits,
        float* __restrict__ rowmax, float* __restrict__ rowsum) {
    int tid = threadIdx.x;
    if (blockIdx.x == 0) {
        __shared__ unsigned int bits[WORDS];   // 8 KB
        __shared__ int wtot[16], wbase[16];
        bits[tid] = 0u; bits[tid + 1024] = 0u;
        if (tid < N_ROWS) { rowS_acc[tid] = 0.f; rowSP_acc[tid] = 0.f; }
        if (tid < M_ROWS) ysum_acc[tid] = 0.f;
        __syncthreads();
        for (int i = tid; i < PN; i += 1024) {
            int p = point_idx[i];
            atomicOr(&bits[p >> 5], 1u << (p & 31));
        }
        __syncthreads();
        unsigned int w0 = bits[tid * 2], w1 = bits[tid * 2 + 1];
        int cnt = __popc(w0) + __popc(w1);
        int lane = tid & 63, wid = tid >> 6;
        int v = cnt;
#pragma unroll
        for (int off = 1; off < 64; off <<= 1) {
            int u = __shfl_up(v, off, 64);
            if (lane >= off) v += u;
        }
        if (lane == 63) wtot[wid] = v;
        __syncthreads();
        if (tid == 0) {
            int run = 0;
#pragma unroll
            for (int i = 0; i < 16; ++i) { wbase[i] = run; run += wtot[i]; }
        }
        __syncthreads();
        int base = wbase[wid] + (v - cnt);          // exclusive rank before word 2*tid
        bitmap_g[tid * 2]     = w0;
        bitmap_g[tid * 2 + 1] = w1;
        rank_g[tid * 2]       = base;
        rank_g[tid * 2 + 1]   = base + __popc(w0);
    } else {
        int wave = tid >> 6, lane = tid & 63;
        int n = (blockIdx.x - 1) * 16 + wave;       // < 400
        const float* row = pred_logits + n * K_CLS;
        float mx = -1e30f;
        for (int k = lane; k < K_CLS; k += 64) mx = fmaxf(mx, row[k]);
#pragma unroll
        for (int off = 32; off > 0; off >>= 1) mx = fmaxf(mx, __shfl_down(mx, off, 64));
        mx = __shfl(mx, 0, 64);
        float se = 0.f;
        for (int k = lane; k < K_CLS; k += 64) se += expf(row[k] - mx);
        se = wave_reduce_sum(se);
        if (lane == 0) { rowmax[n] = mx; rowsum[n] = se; }
    }
}

// --- compact: stream pred_masks/tgt_masks coalesced (f32x4). For selected
//     elements (19%): X rows -> compute x/sig/softplus, write bf16 Xc/Sc at
//     rank + accumulate rowS/rowSP; Y rows -> scatter bf16 into Yb B-frag
//     layout + ysum. Pure stream, no cross-iteration deps: saturates HBM
//     without software pipelining. ---
__global__ __launch_bounds__(256) void compact_kernel(
        const float* __restrict__ pred_masks, const float* __restrict__ tgt_masks,
        const unsigned int* __restrict__ bitmap_g, const int* __restrict__ rank_g,
        __bf16* __restrict__ Xc, __bf16* __restrict__ Sc, __bf16* __restrict__ Yb,
        float* __restrict__ rowS_acc, float* __restrict__ rowSP_acc,
        float* __restrict__ ysum_acc) {
    __shared__ unsigned int sb[CHUNK / 32];   // 512 words = 2 KB
    __shared__ int swb[CHUNK / 32];           // 2 KB
    __shared__ float aS[4], aSP[4];
    int b   = blockIdx.x;
    int row = b / CPB, ch = b % CPB;
    int tid = threadIdx.x;
    int wave = tid >> 6, lane = tid & 63;
    int w0  = ch * (CHUNK / 32);
    sb[tid]        = bitmap_g[w0 + tid];
    sb[tid + 256]  = bitmap_g[w0 + tid + 256];
    swb[tid]       = rank_g[w0 + tid];
    swb[tid + 256] = rank_g[w0 + tid + 256];
    __syncthreads();
    int p0 = ch * CHUNK;

    if (row < N_ROWS) {
        const float* src = pred_masks + (size_t)row * PFULL + p0;
        __bf16* xrow = Xc + (size_t)row * PN;
        __bf16* srow = Sc + (size_t)row * PN;
        float sS = 0.f, sSP = 0.f;
#pragma unroll
        for (int it = 0; it < CHUNK / (256 * 4); ++it) {   // 16 coalesced f32x4
            int e = (it * 256 + tid) * 4;
            f32x4 v = *(const f32x4*)(src + e);
            unsigned int w = sb[e >> 5];
            int r = swb[e >> 5] + __popc(w & ((1u << (e & 31)) - 1u));
            unsigned int m4 = (w >> (e & 31)) & 0xFu;
            if (m4) {
#pragma unroll
                for (int k = 0; k < 4; ++k) if (m4 & (1u << k)) {
                    float x  = v[k];
                    float ax = fabsf(x);
                    float ee = __expf(-ax);
                    float den = 1.f + ee;
                    float inv = __builtin_amdgcn_rcpf(den);
                    float sig = (x >= 0.f) ? inv : ee * inv;
                    float sp  = fmaxf(x, 0.f) + __logf(den);
                    xrow[r] = (__bf16)x;
                    srow[r] = (__bf16)sig;
                    sS += sig; sSP += sp; ++r;
                }
            }
        }
        sS  = wave_reduce_sum(sS);
        sSP = wave_reduce_sum(sSP);
        if (lane == 0) { aS[wave] = sS; aSP[wave] = sSP; }
        __syncthreads();
        if (tid == 0)
            atomicAdd(&rowS_acc[row], aS[0] + aS[1] + aS[2] + aS[3]);
        else if (tid == 1)
            atomicAdd(&rowSP_acc[row], aSP[0] + aSP[1] + aSP[2] + aSP[3]);
    } else {
        int m = row - N_ROWS;
        const float* src = tgt_masks + (size_t)m * PFULL + p0;
        int j = m >> 4, colL = m & 15;
        float ys = 0.f;
#pragma unroll
        for (int it = 0; it < CHUNK / (256 * 4); ++it) {
            int e = (it * 256 + tid) * 4;
            f32x4 v = *(const f32x4*)(src + e);
            unsigned int w = sb[e >> 5];
            int r = swb[e >> 5] + __popc(w & ((1u << (e & 31)) - 1u));
            unsigned int m4 = (w >> (e & 31)) & 0xFu;
            if (m4) {
#pragma unroll
                for (int k = 0; k < 4; ++k) if (m4 & (1u << k)) {
                    float y = (v[k] > 0.5f) ? 1.f : 0.f;
                    int t = r >> 5, rr = r & 31;
                    int quad = rr >> 3, jj = rr & 7;
                    // B-frag layout: lane=quad*16+colL holds k=t*32+quad*8+jj
                    Yb[(((size_t)t * 5 + j) * 64 + quad * 16 + colL) * 8 + jj]
                        = (__bf16)y;
                    ys += y; ++r;
                }
            }
        }
        ys = wave_reduce_sum(ys);
        if (lane == 0) aS[wave] = ys;
        __syncthreads();
        if (tid == 0)
            atomicAdd(&ysum_acc[m], aS[0] + aS[1] + aS[2] + aS[3]);
    }
}

// --- dense compacted bf16 GEMM: A = Xc/Sc (L3-hot, dense 16B loads),
//     B = Yb frags (2 MB, L2-hot). All 14 loads issued up-front, 20 MFMAs.
//     No VALU math, no row sums. Two-pass LDS epilogue (20 KB). ---
__global__ __launch_bounds__(256) void gemm_kernel(
        const __bf16* __restrict__ Xc, const __bf16* __restrict__ Sc,
        const __bf16* __restrict__ Yb,
        float* __restrict__ xypart, float* __restrict__ sypart) {
    __shared__ float red[4][20][64];       // 20 KB
    int tid = threadIdx.x;
    int wave = tid >> 6, lane = tid & 63;
    int colL = lane & 15, quad = lane >> 4;
    int nsub = blockIdx.x % NSUB, kcg = blockIdx.x / NSUB;  // nsub fastest
    int n0 = nsub * 16;
    int tbase = kcg * (TPB * 4) + wave * TPB;
    const bf16x8* Yf = (const bf16x8*)Yb;

    f32x4 accX[5], accS[5];
    f32x4 zero = {0.f, 0.f, 0.f, 0.f};
#pragma unroll
    for (int j = 0; j < 5; ++j) { accX[j] = zero; accS[j] = zero; }

    bf16x8 aX[TPB], aS[TPB], Bb[TPB][5];
#pragma unroll
    for (int i = 0; i < TPB; ++i) {
        int t = tbase + i;
        size_t aoff = (size_t)(n0 + colL) * PN + t * 32 + quad * 8;
        aX[i] = *(const bf16x8*)(Xc + aoff);
        aS[i] = *(const bf16x8*)(Sc + aoff);
        const bf16x8* q = Yf + (size_t)(t * 5) * 64 + lane;
#pragma unroll
        for (int j = 0; j < 5; ++j) Bb[i][j] = q[(size_t)j * 64];
    }
#pragma unroll
    for (int i = 0; i < TPB; ++i) {
#pragma unroll
        for (int j = 0; j < 5; ++j) {
            accX[j] = __builtin_amdgcn_mfma_f32_16x16x32_bf16(aX[i], Bb[i][j], accX[j], 0, 0, 0);
            accS[j] = __builtin_amdgcn_mfma_f32_16x16x32_bf16(aS[i], Bb[i][j], accS[j], 0, 0, 0);
        }
    }

    // ---- epilogue pass 1: xy partials ----
#pragma unroll
    for (int j = 0; j < 5; ++j)
#pragma unroll
        for (int r = 0; r < 4; ++r) red[wave][j * 4 + r][lane] = accX[j][r];
    __syncthreads();
#pragma unroll
    for (int v0 = 0; v0 < 5; ++v0) {
        int v = wave * 5 + v0;
        float s = red[0][v][lane] + red[1][v][lane] + red[2][v][lane] + red[3][v][lane];
        int j = v >> 2, r = v & 3;
        int n = n0 + quad * 4 + r, m = 16 * j + colL;   // verified C/D layout
        xypart[(size_t)kcg * NM + n * M_ROWS + m] = s;
    }
    __syncthreads();
    // ---- epilogue pass 2: sy partials ----
#pragma unroll
    for (int j = 0; j < 5; ++j)
#pragma unroll
        for (int r = 0; r < 4; ++r) red[wave][j * 4 + r][lane] = accS[j][r];
    __syncthreads();
#pragma unroll
    for (int v0 = 0; v0 < 5; ++v0) {
        int v = wave * 5 + v0;
        float s = red[0][v][lane] + red[1][v][lane] + red[2][v][lane] + red[3][v][lane];
        int j = v >> 2, r = v & 3;
        int n = n0 + quad * 4 + r, m = 16 * j + colL;
        sypart[(size_t)kcg * NM + n * M_ROWS + m] = s;
    }
}

// --- combine: reduce 49 xy/sy partials (4 lane-groups) + cost terms.
//     rowS/rowSP/ysum come straight from atomically-built accumulators. ---
__global__ __launch_bounds__(256) void combine_kernel(
        const float* __restrict__ logits,
        const int* __restrict__ tgt_labels,
        const float* __restrict__ rowmax,
        const float* __restrict__ rowsum,
        const float* __restrict__ rowS_acc,
        const float* __restrict__ rowSP_acc,
        const float* __restrict__ ysum_acc,
        const float* __restrict__ xypart,
        const float* __restrict__ sypart,
        float* __restrict__ out) {
    __shared__ float sxy[4][64], ssy[4][64];
    int il = threadIdx.x & 63, q = threadIdx.x >> 6;
    int idx = blockIdx.x * 64 + il;
    int n = idx / M_ROWS, m = idx % M_ROWS;
    float xy = 0.f, sy = 0.f;
    for (int g = q; g < KCG; g += 4) {
        xy += xypart[(size_t)g * NM + idx];
        sy += sypart[(size_t)g * NM + idx];
    }
    sxy[q][il] = xy; ssy[q][il] = sy;
    __syncthreads();
    if (q == 0) {
        xy = sxy[0][il] + sxy[1][il] + sxy[2][il] + sxy[3][il];
        sy = ssy[0][il] + ssy[1][il] + ssy[2][il] + ssy[3][il];
        float ss = rowS_acc[n], sp = rowSP_acc[n], ysum = ysum_acc[m];
        int tc = tgt_labels[m];
        tc = min(max(tc, 0), K_CLS - 1);
        float p = expf(logits[n * K_CLS + tc] - rowmax[n]) / rowsum[n];
        float cost_class = -p;
        float cost_mask = (sp - xy) * (1.0f / PN);
        float cost_dice = 1.f - (2.f * sy + 1.f) / (ss + ysum + 1.f);
        out[idx] = 2.f * cost_class + 5.f * cost_mask + 5.f * cost_dice;
    }
}

extern "C" void kernel_launch(void* const* d_in, const int* in_sizes, int n_in,
                              void* d_out, int out_size, void* d_ws, size_t ws_size,
                              hipStream_t stream) {
    const float* pred_logits = (const float*)d_in[0];   // (4,100,134)
    const float* pred_masks  = (const float*)d_in[1];   // (4,100,256,256)
    const int*   tgt_labels  = (const int*)d_in[2];     // (80,)
    const float* tgt_masks   = (const float*)d_in[3];   // (80,256,256)
    const int*   point_idx   = (const int*)d_in[4];     // (12544,)
    float* out = (float*)d_out;                         // (4,100,80)

    char* ws = (char*)d_ws;
    size_t off = 0;
    auto carve = [&](size_t nbytes) {
        char* p = ws + off;
        off += (nbytes + 255) & ~(size_t)255;
        return p;
    };
    // accumulators zeroed by sort kernel (stream-ordered before compact)
    unsigned int* bitmap = (unsigned int*)carve(WORDS * 4);            // 8 KB
    int*   rankp  = (int*)carve(WORDS * 4);                            // 8 KB
    float* rowmax = (float*)carve(N_ROWS * 4);
    float* rowsum = (float*)carve(N_ROWS * 4);
    float* rowS_acc  = (float*)carve(N_ROWS * 4);
    float* rowSP_acc = (float*)carve(N_ROWS * 4);
    float* ysum_acc  = (float*)carve(M_ROWS * 4);
    __bf16* Xc = (__bf16*)carve((size_t)N_ROWS * PN * 2);              // 10 MB
    __bf16* Sc = (__bf16*)carve((size_t)N_ROWS * PN * 2);              // 10 MB
    __bf16* Yb = (__bf16*)carve((size_t)TSTEPS * 5 * 1024);            // 2.0 MB
    float* xypart = (float*)carve((size_t)KCG * NM * 4);               // 6.3 MB
    float* sypart = (float*)carve((size_t)KCG * NM * 4);               // 6.3 MB
    (void)ws_size; (void)in_sizes; (void)n_in; (void)out_size;

    sort_softmax_kernel<<<26, 1024, 0, stream>>>(
        point_idx, bitmap, rankp, rowS_acc, rowSP_acc, ysum_acc,
        pred_logits, rowmax, rowsum);
    compact_kernel<<<(N_ROWS + M_ROWS) * CPB, 256, 0, stream>>>(
        pred_masks, tgt_masks, bitmap, rankp, Xc, Sc, Yb,
        rowS_acc, rowSP_acc, ysum_acc);
    gemm_kernel<<<NSUB * KCG, 256, 0, stream>>>(Xc, Sc, Yb, xypart, sypart);
    combine_kernel<<<NM / 64, 256, 0, stream>>>(
        pred_logits, tgt_labels, rowmax, rowsum, rowS_acc, rowSP_acc,
        ysum_acc, xypart, sypart, out);
}

// Round 10
// 208.732 us; speedup vs baseline: 1.1202x; 1.0316x over previous
//
#include <hip/hip_runtime.h>
#include <math.h>

#define N_ROWS 400      // bs*Q
#define M_ROWS 80       // = 5*16
#define K_CLS  134
#define PN     12544    // = 392*32 selected points
#define PFULL  65536    // 256*256
#define WORDS  (PFULL / 32)   // 2048 bitmap words
#define TSTEPS 392      // PN/32 MFMA k-steps
#define NSUB   25       // 400/16 n-subtiles
#define KCG    49       // k-groups in gemm (8 t-steps per block)
#define TPB    2        // t-steps per wave
#define NM     (N_ROWS * M_ROWS)
#define CHUNK  8192     // elements per compact block
#define CWORDS (CHUNK / 32)      // 256 bitmap words per chunk
#define CPB    (PFULL / CHUNK)   // 8 chunks per row

typedef __attribute__((ext_vector_type(4))) float  f32x4;
typedef __attribute__((ext_vector_type(8))) __bf16 bf16x8;

__device__ __forceinline__ float wave_reduce_sum(float v) {
#pragma unroll
    for (int off = 32; off > 0; off >>= 1) v += __shfl_down(v, off, 64);
    return v;
}

// --- block 0: selection bitmap + per-word exclusive rank prefix + zero accs.
//     blocks 1..25: softmax stats (16 rows each, one per wave). ---
__global__ __launch_bounds__(1024) void sort_softmax_kernel(
        const int* __restrict__ point_idx,
        unsigned int* __restrict__ bitmap_g, int* __restrict__ rank_g,
        float* __restrict__ rowS_acc, float* __restrict__ rowSP_acc,
        float* __restrict__ ysum_acc,
        const float* __restrict__ pred_logits,
        float* __restrict__ rowmax, float* __restrict__ rowsum) {
    int tid = threadIdx.x;
    if (blockIdx.x == 0) {
        __shared__ unsigned int bits[WORDS];   // 8 KB
        __shared__ int wtot[16], wbase[16];
        bits[tid] = 0u; bits[tid + 1024] = 0u;
        if (tid < N_ROWS) { rowS_acc[tid] = 0.f; rowSP_acc[tid] = 0.f; }
        if (tid < M_ROWS) ysum_acc[tid] = 0.f;
        __syncthreads();
        for (int i = tid; i < PN; i += 1024) {
            int p = point_idx[i];
            atomicOr(&bits[p >> 5], 1u << (p & 31));
        }
        __syncthreads();
        unsigned int w0 = bits[tid * 2], w1 = bits[tid * 2 + 1];
        int cnt = __popc(w0) + __popc(w1);
        int lane = tid & 63, wid = tid >> 6;
        int v = cnt;
#pragma unroll
        for (int off = 1; off < 64; off <<= 1) {
            int u = __shfl_up(v, off, 64);
            if (lane >= off) v += u;
        }
        if (lane == 63) wtot[wid] = v;
        __syncthreads();
        if (tid == 0) {
            int run = 0;
#pragma unroll
            for (int i = 0; i < 16; ++i) { wbase[i] = run; run += wtot[i]; }
        }
        __syncthreads();
        int base = wbase[wid] + (v - cnt);          // exclusive rank before word 2*tid
        bitmap_g[tid * 2]     = w0;
        bitmap_g[tid * 2 + 1] = w1;
        rank_g[tid * 2]       = base;
        rank_g[tid * 2 + 1]   = base + __popc(w0);
    } else {
        int wave = tid >> 6, lane = tid & 63;
        int n = (blockIdx.x - 1) * 16 + wave;       // < 400
        const float* row = pred_logits + n * K_CLS;
        float mx = -1e30f;
        for (int k = lane; k < K_CLS; k += 64) mx = fmaxf(mx, row[k]);
#pragma unroll
        for (int off = 32; off > 0; off >>= 1) mx = fmaxf(mx, __shfl_down(mx, off, 64));
        mx = __shfl(mx, 0, 64);
        float se = 0.f;
        for (int k = lane; k < K_CLS; k += 64) se += expf(row[k] - mx);
        se = wave_reduce_sum(se);
        if (lane == 0) { rowmax[n] = mx; rowsum[n] = se; }
    }
}

// --- compact v2: phase 1 scatters selected bf16 values to LDS at their
//     block-local rank (1 predicated ds_write per element, per-k rank via
//     popc -- no serial chain, no math under divergence). Phase 2 runs the
//     sigmoid/softplus math DENSE (100% active lanes) over the compacted
//     LDS buffer and writes Xc/Sc/Yc with contiguous coalesced stores.
//     Yc is plain dense [m][k] bf16 -- B-fragments are 8 consecutive k for
//     fixed m, so the GEMM loads B directly from Yc (no fragment scatter). ---
__global__ __launch_bounds__(256) void compact_kernel(
        const float* __restrict__ pred_masks, const float* __restrict__ tgt_masks,
        const unsigned int* __restrict__ bitmap_g, const int* __restrict__ rank_g,
        __bf16* __restrict__ Xc, __bf16* __restrict__ Sc, __bf16* __restrict__ Yc,
        float* __restrict__ rowS_acc, float* __restrict__ rowSP_acc,
        float* __restrict__ ysum_acc) {
    __shared__ __bf16 comp[CHUNK];            // 16 KB (worst-case all selected)
    __shared__ unsigned int sb[CWORDS];       // 1 KB
    __shared__ int swb[CWORDS];               // 1 KB (block-local ranks)
    __shared__ float a0[4], a1[4];
    int b   = blockIdx.x;
    int row = b / CPB, ch = b % CPB;
    int tid = threadIdx.x;
    int wave = tid >> 6, lane = tid & 63;
    int w0  = ch * CWORDS;
    int gb  = rank_g[w0];                      // chunk's global compacted base
    int end = (w0 + CWORDS == WORDS) ? PN : rank_g[w0 + CWORDS];
    int cnt = end - gb;
    sb[tid]  = bitmap_g[w0 + tid];
    swb[tid] = rank_g[w0 + tid] - gb;
    __syncthreads();
    int p0 = ch * CHUNK;
    bool isX = (row < N_ROWS);
    const float* src = isX ? (pred_masks + (size_t)row * PFULL + p0)
                           : (tgt_masks + (size_t)(row - N_ROWS) * PFULL + p0);

    // ---- phase 1: scatter selected values to LDS at local rank ----
#pragma unroll
    for (int it = 0; it < CHUNK / (256 * 4); ++it) {   // 8 coalesced f32x4
        int e = (it * 256 + tid) * 4;
        f32x4 v = *(const f32x4*)(src + e);
        unsigned int w = sb[e >> 5];
        int bp = e & 31;
        int r0 = swb[e >> 5] + __popc(w & ((1u << bp) - 1u));
        unsigned int m4 = (w >> bp) & 0xFu;
        if (isX) {
            if (m4 & 1u) comp[r0] = (__bf16)v[0];
            if (m4 & 2u) comp[r0 + __popc(m4 & 1u)] = (__bf16)v[1];
            if (m4 & 4u) comp[r0 + __popc(m4 & 3u)] = (__bf16)v[2];
            if (m4 & 8u) comp[r0 + __popc(m4 & 7u)] = (__bf16)v[3];
        } else {
            if (m4 & 1u) comp[r0] = (__bf16)((v[0] > 0.5f) ? 1.f : 0.f);
            if (m4 & 2u) comp[r0 + __popc(m4 & 1u)] = (__bf16)((v[1] > 0.5f) ? 1.f : 0.f);
            if (m4 & 4u) comp[r0 + __popc(m4 & 3u)] = (__bf16)((v[2] > 0.5f) ? 1.f : 0.f);
            if (m4 & 8u) comp[r0 + __popc(m4 & 7u)] = (__bf16)((v[3] > 0.5f) ? 1.f : 0.f);
        }
    }
    __syncthreads();

    // ---- phase 2: dense math + coalesced stores ----
    if (isX) {
        __bf16* xrow = Xc + (size_t)row * PN + gb;
        __bf16* srow = Sc + (size_t)row * PN + gb;
        float sS = 0.f, sSP = 0.f;
        for (int i = tid; i < cnt; i += 256) {
            __bf16 xb = comp[i];
            float x  = (float)xb;
            float ax = fabsf(x);
            float ee = __expf(-ax);
            float den = 1.f + ee;
            float inv = __builtin_amdgcn_rcpf(den);
            float sig = (x >= 0.f) ? inv : ee * inv;
            float sp  = fmaxf(x, 0.f) + __logf(den);
            xrow[i] = xb;
            srow[i] = (__bf16)sig;
            sS += sig; sSP += sp;
        }
        sS  = wave_reduce_sum(sS);
        sSP = wave_reduce_sum(sSP);
        if (lane == 0) { a0[wave] = sS; a1[wave] = sSP; }
        __syncthreads();
        if (tid == 0)
            atomicAdd(&rowS_acc[row], a0[0] + a0[1] + a0[2] + a0[3]);
        else if (tid == 1)
            atomicAdd(&rowSP_acc[row], a1[0] + a1[1] + a1[2] + a1[3]);
    } else {
        int m = row - N_ROWS;
        __bf16* yrow = Yc + (size_t)m * PN + gb;
        float ys = 0.f;
        for (int i = tid; i < cnt; i += 256) {
            __bf16 y = comp[i];
            yrow[i] = y;
            ys += (float)y;
        }
        ys = wave_reduce_sum(ys);
        if (lane == 0) a0[wave] = ys;
        __syncthreads();
        if (tid == 0)
            atomicAdd(&ysum_acc[m], a0[0] + a0[1] + a0[2] + a0[3]);
    }
}

// --- dense compacted bf16 GEMM: A = Xc/Sc, B = Yc (dense [m][k]; the
//     B-fragment at lane l is 8 consecutive k for fixed m = direct bf16x8
//     load). All 14 loads issued up-front, 20 MFMAs, two-pass LDS epilogue. ---
__global__ __launch_bounds__(256) void gemm_kernel(
        const __bf16* __restrict__ Xc, const __bf16* __restrict__ Sc,
        const __bf16* __restrict__ Yc,
        float* __restrict__ xypart, float* __restrict__ sypart) {
    __shared__ float red[4][20][64];       // 20 KB
    int tid = threadIdx.x;
    int wave = tid >> 6, lane = tid & 63;
    int colL = lane & 15, quad = lane >> 4;
    int nsub = blockIdx.x % NSUB, kcg = blockIdx.x / NSUB;  // nsub fastest
    int n0 = nsub * 16;
    int tbase = kcg * (TPB * 4) + wave * TPB;

    f32x4 accX[5], accS[5];
    f32x4 zero = {0.f, 0.f, 0.f, 0.f};
#pragma unroll
    for (int j = 0; j < 5; ++j) { accX[j] = zero; accS[j] = zero; }

    bf16x8 aX[TPB], aS[TPB], Bb[TPB][5];
#pragma unroll
    for (int i = 0; i < TPB; ++i) {
        int t = tbase + i;
        int k0 = t * 32 + quad * 8;
        size_t aoff = (size_t)(n0 + colL) * PN + k0;
        aX[i] = *(const bf16x8*)(Xc + aoff);
        aS[i] = *(const bf16x8*)(Sc + aoff);
#pragma unroll
        for (int j = 0; j < 5; ++j)
            Bb[i][j] = *(const bf16x8*)(Yc + (size_t)(16 * j + colL) * PN + k0);
    }
#pragma unroll
    for (int i = 0; i < TPB; ++i) {
#pragma unroll
        for (int j = 0; j < 5; ++j) {
            accX[j] = __builtin_amdgcn_mfma_f32_16x16x32_bf16(aX[i], Bb[i][j], accX[j], 0, 0, 0);
            accS[j] = __builtin_amdgcn_mfma_f32_16x16x32_bf16(aS[i], Bb[i][j], accS[j], 0, 0, 0);
        }
    }

    // ---- epilogue pass 1: xy partials ----
#pragma unroll
    for (int j = 0; j < 5; ++j)
#pragma unroll
        for (int r = 0; r < 4; ++r) red[wave][j * 4 + r][lane] = accX[j][r];
    __syncthreads();
#pragma unroll
    for (int v0 = 0; v0 < 5; ++v0) {
        int v = wave * 5 + v0;
        float s = red[0][v][lane] + red[1][v][lane] + red[2][v][lane] + red[3][v][lane];
        int j = v >> 2, r = v & 3;
        int n = n0 + quad * 4 + r, m = 16 * j + colL;   // verified C/D layout
        xypart[(size_t)kcg * NM + n * M_ROWS + m] = s;
    }
    __syncthreads();
    // ---- epilogue pass 2: sy partials ----
#pragma unroll
    for (int j = 0; j < 5; ++j)
#pragma unroll
        for (int r = 0; r < 4; ++r) red[wave][j * 4 + r][lane] = accS[j][r];
    __syncthreads();
#pragma unroll
    for (int v0 = 0; v0 < 5; ++v0) {
        int v = wave * 5 + v0;
        float s = red[0][v][lane] + red[1][v][lane] + red[2][v][lane] + red[3][v][lane];
        int j = v >> 2, r = v & 3;
        int n = n0 + quad * 4 + r, m = 16 * j + colL;
        sypart[(size_t)kcg * NM + n * M_ROWS + m] = s;
    }
}

// --- combine: reduce 49 xy/sy partials (4 lane-groups) + cost terms. ---
__global__ __launch_bounds__(256) void combine_kernel(
        const float* __restrict__ logits,
        const int* __restrict__ tgt_labels,
        const float* __restrict__ rowmax,
        const float* __restrict__ rowsum,
        const float* __restrict__ rowS_acc,
        const float* __restrict__ rowSP_acc,
        const float* __restrict__ ysum_acc,
        const float* __restrict__ xypart,
        const float* __restrict__ sypart,
        float* __restrict__ out) {
    __shared__ float sxy[4][64], ssy[4][64];
    int il = threadIdx.x & 63, q = threadIdx.x >> 6;
    int idx = blockIdx.x * 64 + il;
    int n = idx / M_ROWS, m = idx % M_ROWS;
    float xy = 0.f, sy = 0.f;
    for (int g = q; g < KCG; g += 4) {
        xy += xypart[(size_t)g * NM + idx];
        sy += sypart[(size_t)g * NM + idx];
    }
    sxy[q][il] = xy; ssy[q][il] = sy;
    __syncthreads();
    if (q == 0) {
        xy = sxy[0][il] + sxy[1][il] + sxy[2][il] + sxy[3][il];
        sy = ssy[0][il] + ssy[1][il] + ssy[2][il] + ssy[3][il];
        float ss = rowS_acc[n], sp = rowSP_acc[n], ysum = ysum_acc[m];
        int tc = tgt_labels[m];
        tc = min(max(tc, 0), K_CLS - 1);
        float p = expf(logits[n * K_CLS + tc] - rowmax[n]) / rowsum[n];
        float cost_class = -p;
        float cost_mask = (sp - xy) * (1.0f / PN);
        float cost_dice = 1.f - (2.f * sy + 1.f) / (ss + ysum + 1.f);
        out[idx] = 2.f * cost_class + 5.f * cost_mask + 5.f * cost_dice;
    }
}

extern "C" void kernel_launch(void* const* d_in, const int* in_sizes, int n_in,
                              void* d_out, int out_size, void* d_ws, size_t ws_size,
                              hipStream_t stream) {
    const float* pred_logits = (const float*)d_in[0];   // (4,100,134)
    const float* pred_masks  = (const float*)d_in[1];   // (4,100,256,256)
    const int*   tgt_labels  = (const int*)d_in[2];     // (80,)
    const float* tgt_masks   = (const float*)d_in[3];   // (80,256,256)
    const int*   point_idx   = (const int*)d_in[4];     // (12544,)
    float* out = (float*)d_out;                         // (4,100,80)

    char* ws = (char*)d_ws;
    size_t off = 0;
    auto carve = [&](size_t nbytes) {
        char* p = ws + off;
        off += (nbytes + 255) & ~(size_t)255;
        return p;
    };
    // accumulators zeroed by sort kernel (stream-ordered before compact)
    unsigned int* bitmap = (unsigned int*)carve(WORDS * 4);            // 8 KB
    int*   rankp  = (int*)carve(WORDS * 4);                            // 8 KB
    float* rowmax = (float*)carve(N_ROWS * 4);
    float* rowsum = (float*)carve(N_ROWS * 4);
    float* rowS_acc  = (float*)carve(N_ROWS * 4);
    float* rowSP_acc = (float*)carve(N_ROWS * 4);
    float* ysum_acc  = (float*)carve(M_ROWS * 4);
    __bf16* Xc = (__bf16*)carve((size_t)N_ROWS * PN * 2);              // 10 MB
    __bf16* Sc = (__bf16*)carve((size_t)N_ROWS * PN * 2);              // 10 MB
    __bf16* Yc = (__bf16*)carve((size_t)M_ROWS * PN * 2);              // 2.0 MB
    float* xypart = (float*)carve((size_t)KCG * NM * 4);               // 6.3 MB
    float* sypart = (float*)carve((size_t)KCG * NM * 4);               // 6.3 MB
    (void)ws_size; (void)in_sizes; (void)n_in; (void)out_size;

    sort_softmax_kernel<<<26, 1024, 0, stream>>>(
        point_idx, bitmap, rankp, rowS_acc, rowSP_acc, ysum_acc,
        pred_logits, rowmax, rowsum);
    compact_kernel<<<(N_ROWS + M_ROWS) * CPB, 256, 0, stream>>>(
        pred_masks, tgt_masks, bitmap, rankp, Xc, Sc, Yc,
        rowS_acc, rowSP_acc, ysum_acc);
    gemm_kernel<<<NSUB * KCG, 256, 0, stream>>>(Xc, Sc, Yc, xypart, sypart);
    combine_kernel<<<NM / 64, 256, 0, stream>>>(
        pred_logits, tgt_labels, rowmax, rowsum, rowS_acc, rowSP_acc,
        ysum_acc, xypart, sypart, out);
}